// Round 3
// baseline (1682.492 us; speedup 1.0000x reference)
//
#include <hip/hip_runtime.h>

// ---- model constants ----
#define D_    1024
#define T_    1024
#define H_    16
#define HD_   64
#define NL    3
#define VOC   32000
#define BAT   2
#define MR    (BAT*T_)   // 2048 rows

typedef unsigned short u16;
typedef unsigned int   u32;
typedef __bf16 bf16x8 __attribute__((ext_vector_type(8)));
typedef float  f32x4  __attribute__((ext_vector_type(4)));

__device__ __forceinline__ u16 f2b(float f){
  u32 u = __float_as_uint(f);
  u += 0x7fffu + ((u >> 16) & 1u);          // RNE; inputs finite
  return (u16)(u >> 16);
}
__device__ __forceinline__ float blo(u32 w){ return __uint_as_float(w << 16); }
__device__ __forceinline__ float bhi(u32 w){ return __uint_as_float(w & 0xffff0000u); }
__device__ __forceinline__ u32 pk2(float a, float b){ return (u32)f2b(a) | ((u32)f2b(b) << 16); }

// async global->LDS, 16B per lane; LDS dest is wave-uniform base + lane*16 (linear)
__device__ __forceinline__ void gload16(const u16* g, u16* l){
  __builtin_amdgcn_global_load_lds(
      (const __attribute__((address_space(1))) void*)g,
      (__attribute__((address_space(3))) void*)l, 16, 0, 0);
}

// ---- embedding: x[bt][d] = tok_emb[idx[bt]][d] + pos_emb[t][d] ----
__global__ __launch_bounds__(256) void embed_k(const int* __restrict__ idx,
    const float* __restrict__ tok, const float* __restrict__ pos, float* __restrict__ x){
  int bt = blockIdx.x, tid = threadIdx.x;
  int t = bt & (T_-1);
  int tk = idx[bt];
  float4 a = ((const float4*)(tok + (size_t)tk * D_))[tid];
  float4 p = ((const float4*)(pos + (size_t)t  * D_))[tid];
  a.x += p.x; a.y += p.y; a.z += p.z; a.w += p.w;
  ((float4*)(x + (size_t)bt * D_))[tid] = a;
}

// ---- layernorm (f32 in, bf16 out), one block per row of 1024 ----
__global__ __launch_bounds__(256) void ln_k(const float* __restrict__ x,
    const float* __restrict__ g, const float* __restrict__ b, u16* __restrict__ out){
  int row = blockIdx.x, tid = threadIdx.x;
  float4 v = ((const float4*)(x + (size_t)row * D_))[tid];
  float s = v.x+v.y+v.z+v.w;
  float q = v.x*v.x+v.y*v.y+v.z*v.z+v.w*v.w;
  #pragma unroll
  for (int off = 32; off >= 1; off >>= 1){
    s += __shfl_xor(s, off);
    q += __shfl_xor(q, off);
  }
  __shared__ float ss[4], sq[4];
  int wave = tid >> 6;
  if ((tid & 63) == 0){ ss[wave] = s; sq[wave] = q; }
  __syncthreads();
  s = ss[0]+ss[1]+ss[2]+ss[3];
  q = sq[0]+sq[1]+sq[2]+sq[3];
  float mean = s * (1.f/D_);
  float var  = q * (1.f/D_) - mean*mean;
  float rs = rsqrtf(var + 1e-5f);
  float4 gg = ((const float4*)g)[tid];
  float4 bb = ((const float4*)b)[tid];
  u32 p0 = pk2((v.x-mean)*rs*gg.x+bb.x, (v.y-mean)*rs*gg.y+bb.y);
  u32 p1 = pk2((v.z-mean)*rs*gg.z+bb.z, (v.w-mean)*rs*gg.w+bb.w);
  ((uint2*)(out + (size_t)row * D_))[tid] = make_uint2(p0, p1);
}

// ---- weight repack: f32 [K,N] -> bf16 [N,K] (B^T), LDS-tiled transpose ----
__global__ __launch_bounds__(1024) void repack_t_k(const float* __restrict__ src,
    u16* __restrict__ dst, int K, int N, size_t sstride, size_t dstride){
  __shared__ float tile[32][33];
  int l = blockIdx.z;
  const float* s = src + (size_t)l * sstride;
  u16* d = dst + (size_t)l * dstride;
  int n0 = blockIdx.x << 5, k0 = blockIdx.y << 5;
  int tx = threadIdx.x, ty = threadIdx.y;
  tile[ty][tx] = s[(size_t)(k0 + ty) * N + n0 + tx];
  __syncthreads();
  d[(size_t)(n0 + ty) * K + k0 + tx] = f2b(tile[tx][ty]);
}

// ---- qkv repack: wq/wk/wv (L,H,D,HD) f32 -> bf16 [L][3072][1024] (n = which*1024+h*64+hd, transposed vs d) ----
__global__ __launch_bounds__(1024) void repack_qkv_k(const float* __restrict__ wq,
    const float* __restrict__ wk, const float* __restrict__ wv, u16* __restrict__ dst){
  __shared__ float tile[32][33];
  int l = blockIdx.z;
  int d0 = blockIdx.x << 5;
  int n0 = blockIdx.y << 5;
  int which = n0 >> 10, within = n0 & 1023;
  int hh = within >> 6, hd0 = within & 63;
  const float* src = (which == 0 ? wq : (which == 1 ? wk : wv))
                     + ((size_t)l * H_ + hh) * (D_ * HD_);
  int tx = threadIdx.x, ty = threadIdx.y;
  tile[ty][tx] = src[(size_t)(d0 + ty) * HD_ + hd0 + tx];
  __syncthreads();
  dst[((size_t)l * 3072 + n0 + ty) * D_ + d0 + tx] = f2b(tile[tx][ty]);
}

// ---- bf16 MFMA GEMM: C[M,N] = A[M,K] @ Bt[N,K]^T (+bias)(+resid)(relu?) ----
// 128x128 tile, BK=32, 4 waves, each wave 64x64 via 4x4 mfma_f32_16x16x32_bf16.
// Staging via global_load_lds width=16 (linear LDS dest); LDS bank-conflict fix via
// XOR swizzle of the 16B segment index with (row>>1)&3, applied to the GLOBAL source
// address (involution) and the ds_read address -- dest stays linear (rule #21).
// Block->tile order is group-major (8 n-tiles x all m-tiles) for B-panel L2/L3 reuse.
__global__ __launch_bounds__(256) void gemm_k(
    const u16* __restrict__ A, const u16* __restrict__ Bt,
    const float* __restrict__ bias, const float* __restrict__ resid,
    float* __restrict__ Cf, u16* __restrict__ Cb,
    int M, int N, int K, int relu)
{
  __shared__ __attribute__((aligned(16))) u16 Als[128*32];
  __shared__ __attribute__((aligned(16))) u16 Bls[128*32];
  int tiles_m = M >> 7, tiles_n = N >> 7;
  int tm, tn;
  {
    const int GN = 8;
    int full = tiles_n / GN;
    int fullsz = full * GN * tiles_m;
    int bid = blockIdx.x;
    if (bid < fullsz){
      int g = bid / (GN * tiles_m);
      int r = bid % (GN * tiles_m);
      tm = r / GN; tn = g * GN + (r % GN);
    } else {
      int r = bid - fullsz;
      int remn = tiles_n - full * GN;
      tm = r / remn; tn = full * GN + (r % remn);
    }
  }
  int m0 = tm << 7, n0 = tn << 7;
  int tid = threadIdx.x, lane = tid & 63, wave = tid >> 6;
  int wm = (wave >> 1) << 6, wn = (wave & 1) << 6;
  f32x4 acc[4][4];
  f32x4 zero = {0.f, 0.f, 0.f, 0.f};
  #pragma unroll
  for (int i = 0; i < 4; i++)
    #pragma unroll
    for (int j = 0; j < 4; j++) acc[i][j] = zero;

  // staging geometry: wave w covers LDS rows [w*16, w*16+16) and +64; lane l -> row w*16+(l>>2), seg l&3
  int lrow = lane >> 2, lseg = lane & 3;
  int arow = wave*16 + lrow;                 // LDS row index (first half)
  int ssw  = (arow >> 1) & 3;                // segment swizzle ((row+64) gives same)
  int scol = ((lseg ^ ssw) << 3);            // swizzled source column (elements)
  const u16* Ag0 = A  + (size_t)(m0 + arow) * K + scol;
  const u16* Ag1 = Ag0 + (size_t)64 * K;
  const u16* Bg0 = Bt + (size_t)(n0 + arow) * K + scol;
  const u16* Bg1 = Bg0 + (size_t)64 * K;
  u16* Al0 = Als + wave*512;                 // 16 rows * 32 elems
  u16* Al1 = Als + 64*32 + wave*512;
  u16* Bl0 = Bls + wave*512;
  u16* Bl1 = Bls + 64*32 + wave*512;

  int fr = lane & 15;
  int fqs = (((lane >> 4) ^ ((fr >> 1) & 3)) << 3);   // swizzled read offset within row
  for (int k0 = 0; k0 < K; k0 += 32){
    __syncthreads();                         // prev iter done reading LDS
    gload16(Ag0 + k0, Al0);
    gload16(Ag1 + k0, Al1);
    gload16(Bg0 + k0, Bl0);
    gload16(Bg1 + k0, Bl1);
    __syncthreads();                         // drains vmcnt: staged data ready
    bf16x8 af[4], bfr[4];
    #pragma unroll
    for (int i = 0; i < 4; i++) af[i]  = *(const bf16x8*)(Als + (wm + i*16 + fr)*32 + fqs);
    #pragma unroll
    for (int i = 0; i < 4; i++) bfr[i] = *(const bf16x8*)(Bls + (wn + i*16 + fr)*32 + fqs);
    #pragma unroll
    for (int mi = 0; mi < 4; mi++)
      #pragma unroll
      for (int ni = 0; ni < 4; ni++)
        acc[mi][ni] = __builtin_amdgcn_mfma_f32_16x16x32_bf16(af[mi], bfr[ni], acc[mi][ni], 0, 0, 0);
  }
  // epilogue: C/D layout col=lane&15, row=(lane>>4)*4+reg  [guide-verified m89/m91]
  int cn = lane & 15, rq = (lane >> 4) << 2;
  #pragma unroll
  for (int mi = 0; mi < 4; mi++){
    #pragma unroll
    for (int ni = 0; ni < 4; ni++){
      int c = n0 + wn + ni*16 + cn;
      float bv = bias ? bias[c] : 0.f;
      #pragma unroll
      for (int r = 0; r < 4; r++){
        int rr = m0 + wm + mi*16 + rq + r;
        float v = acc[mi][ni][r] + bv;
        if (resid) v += resid[(size_t)rr * N + c];
        if (relu)  v = fmaxf(v, 0.f);
        if (Cf) Cf[(size_t)rr * N + c] = v;
        if (Cb) Cb[(size_t)rr * N + c] = f2b(v);
      }
    }
  }
}

// ---- MFMA causal flash attention ----
// grid: B*H*(T/64) = 512 blocks, 256 thr = 4 waves; each wave owns 16 query rows.
// qkv: [B*T][3072] bf16 (q|k|v, each [*][h*64+d]); out: [B*T][1024] bf16 (h-major)
__global__ __launch_bounds__(256) void attn_k(const u16* __restrict__ qkv, u16* __restrict__ out){
  __shared__ u16 kls[64][72];        // K[s][d]
  __shared__ u16 vtls[64][72];       // V^T[d][s]
  __shared__ u16 pls[4][16][72];     // per-wave P tile [q][s]
  int bid = blockIdx.x;
  int qt = bid & 15, bh = bid >> 4;          // 16 q-tiles of 64 rows
  int h = bh & (H_-1), b = bh >> 4;
  int q0 = qt << 6;
  int tid = threadIdx.x, lane = tid & 63, wave = tid >> 6;
  int fr = lane & 15, fq = (lane >> 4) << 3; // A/B frag: row/col = lane&15, k = (lane>>4)*8
  int cn = fr, rq = (lane >> 4) << 2;        // C frag: col = lane&15, row = (lane>>4)*4 + r

  // Q fragments (16 rows x 64 cols per wave), loaded once
  const u16* qp = qkv + ((size_t)(b*T_ + q0 + wave*16 + fr) * 3072 + h*64);
  bf16x8 qa0 = *(const bf16x8*)(qp + fq);
  bf16x8 qa1 = *(const bf16x8*)(qp + 32 + fq);

  f32x4 acc[4];
  f32x4 zero = {0.f,0.f,0.f,0.f};
  #pragma unroll
  for (int i = 0; i < 4; i++) acc[i] = zero;
  float mrun[4], lrun[4];
  #pragma unroll
  for (int r = 0; r < 4; r++){ mrun[r] = -1e30f; lrun[r] = 0.f; }

  // staging: rows 0..31 (+32 partner), 8 threads per row cover all 64 cols
  int ldrow = tid >> 3, ldseg = tid & 7;
  const u16* kbase = qkv + ((size_t)(b*T_ + ldrow) * 3072 + 1024 + h*64 + ldseg*8);
  const size_t rstep = (size_t)32 * 3072;

  for (int ch = 0; ch <= qt; ch++){
    const u16* kp = kbase + (size_t)(ch << 6) * 3072;
    uint4 kv0 = *(const uint4*)kp;
    uint4 kv1 = *(const uint4*)(kp + rstep);
    uint4 vv0 = *(const uint4*)(kp + 1024);
    uint4 vv1 = *(const uint4*)(kp + rstep + 1024);
    __syncthreads();                          // prev iter done reading kls/vtls
    *(uint4*)(&kls[ldrow][ldseg*8])      = kv0;
    *(uint4*)(&kls[ldrow + 32][ldseg*8]) = kv1;
    union { uint4 u; u16 s[8]; } vu0, vu1; vu0.u = vv0; vu1.u = vv1;
    #pragma unroll
    for (int j = 0; j < 8; j++){
      vtls[ldseg*8 + j][ldrow]      = vu0.s[j];
      vtls[ldseg*8 + j][ldrow + 32] = vu1.s[j];
    }
    __syncthreads();

    // S = Q @ K^T  (16x64 per wave)
    f32x4 sf[4];
    #pragma unroll
    for (int ni = 0; ni < 4; ni++) sf[ni] = zero;
    #pragma unroll
    for (int ni = 0; ni < 4; ni++){
      bf16x8 kb0 = *(const bf16x8*)(&kls[ni*16 + fr][fq]);
      bf16x8 kb1 = *(const bf16x8*)(&kls[ni*16 + fr][32 + fq]);
      sf[ni] = __builtin_amdgcn_mfma_f32_16x16x32_bf16(qa0, kb0, sf[ni], 0, 0, 0);
      sf[ni] = __builtin_amdgcn_mfma_f32_16x16x32_bf16(qa1, kb1, sf[ni], 0, 0, 0);
    }

    int s0 = ch << 6;
    float sv[4][4];
    if (ch == qt){                            // diagonal chunk: causal mask
      #pragma unroll
      for (int ni = 0; ni < 4; ni++)
        #pragma unroll
        for (int r = 0; r < 4; r++){
          int srow = s0 + ni*16 + cn;
          int qrow = q0 + wave*16 + rq + r;
          sv[ni][r] = (srow <= qrow) ? sf[ni][r]*0.125f : -1e30f;
        }
    } else {
      #pragma unroll
      for (int ni = 0; ni < 4; ni++)
        #pragma unroll
        for (int r = 0; r < 4; r++) sv[ni][r] = sf[ni][r]*0.125f;
    }

    // online softmax: row = 16 lanes sharing (lane>>4), reduce via shfl_xor 1..8
    #pragma unroll
    for (int r = 0; r < 4; r++){
      float mx = fmaxf(fmaxf(sv[0][r], sv[1][r]), fmaxf(sv[2][r], sv[3][r]));
      #pragma unroll
      for (int off = 8; off >= 1; off >>= 1) mx = fmaxf(mx, __shfl_xor(mx, off));
      float mn = fmaxf(mrun[r], mx);
      float al = __expf(mrun[r] - mn);
      mrun[r] = mn;
      float ps = 0.f;
      #pragma unroll
      for (int ni = 0; ni < 4; ni++){
        float p = __expf(sv[ni][r] - mn);
        sv[ni][r] = p; ps += p;
      }
      #pragma unroll
      for (int off = 8; off >= 1; off >>= 1) ps += __shfl_xor(ps, off);
      lrun[r] = lrun[r]*al + ps;
      #pragma unroll
      for (int ni = 0; ni < 4; ni++) acc[ni][r] *= al;
    }

    // P (C layout) -> LDS -> A-fragments
    #pragma unroll
    for (int ni = 0; ni < 4; ni++)
      #pragma unroll
      for (int r = 0; r < 4; r++)
        pls[wave][rq + r][ni*16 + cn] = f2b(sv[ni][r]);
    __syncthreads();

    // O += P @ V   (A = P[q][s], Bt = V^T[d][s])
    #pragma unroll
    for (int kk = 0; kk < 2; kk++){
      bf16x8 pa = *(const bf16x8*)(&pls[wave][fr][kk*32 + fq]);
      #pragma unroll
      for (int di = 0; di < 4; di++){
        bf16x8 vb = *(const bf16x8*)(&vtls[di*16 + fr][kk*32 + fq]);
        acc[di] = __builtin_amdgcn_mfma_f32_16x16x32_bf16(pa, vb, acc[di], 0, 0, 0);
      }
    }
  }

  u16* ob = out + ((size_t)(b*T_ + q0 + wave*16) * D_ + h*64);
  #pragma unroll
  for (int r = 0; r < 4; r++){
    float inv = 1.f / lrun[r];
    #pragma unroll
    for (int di = 0; di < 4; di++)
      ob[(size_t)(rq + r) * D_ + di*16 + cn] = f2b(acc[di][r] * inv);
  }
}

extern "C" void kernel_launch(void* const* d_in, const int* in_sizes, int n_in,
                              void* d_out, int out_size, void* d_ws, size_t ws_size,
                              hipStream_t stream){
  (void)in_sizes; (void)n_in; (void)out_size; (void)ws_size;
  const int*   idx     = (const int*)  d_in[0];
  const float* tok_emb = (const float*)d_in[1];
  const float* pos_emb = (const float*)d_in[2];
  const float* wq      = (const float*)d_in[3];
  const float* wk      = (const float*)d_in[4];
  const float* wv      = (const float*)d_in[5];
  const float* w_proj  = (const float*)d_in[6];
  const float* b_proj  = (const float*)d_in[7];
  const float* w1      = (const float*)d_in[8];
  const float* b1      = (const float*)d_in[9];
  const float* w2      = (const float*)d_in[10];
  const float* b2      = (const float*)d_in[11];
  const float* ln1g    = (const float*)d_in[12];
  const float* ln1b    = (const float*)d_in[13];
  const float* ln2g    = (const float*)d_in[14];
  const float* ln2b    = (const float*)d_in[15];
  const float* lnfg    = (const float*)d_in[16];
  const float* lnfb    = (const float*)d_in[17];
  const float* w_lm    = (const float*)d_in[18];
  const float* b_lm    = (const float*)d_in[19];

  char* ws = (char*)d_ws;
  size_t off = 0;
  auto alloc = [&](size_t bytes)->char*{
    char* p = ws + off; off += (bytes + 255) & ~(size_t)255; return p;
  };
  u16*   qkvT  = (u16*)  alloc((size_t)NL*3072*1024*2);
  u16*   projT = (u16*)  alloc((size_t)NL*1024*1024*2);
  u16*   w1T   = (u16*)  alloc((size_t)NL*4096*1024*2);
  u16*   w2T   = (u16*)  alloc((size_t)NL*1024*4096*2);
  u16*   wlmT  = (u16*)  alloc((size_t)VOC*1024*2);
  float* x     = (float*)alloc((size_t)MR*1024*4);
  u16*   hbuf  = (u16*)  alloc((size_t)MR*1024*2);
  u16*   qkvb  = (u16*)  alloc((size_t)MR*3072*2);
  u16*   attnb = (u16*)  alloc((size_t)MR*1024*2);
  float* sa    = (float*)alloc((size_t)MR*1024*4);
  u16*   ff1   = (u16*)  alloc((size_t)MR*4096*2);

  auto gemm = [&](const u16* A, const u16* Bt, const float* bias, const float* resid,
                  float* Cf, u16* Cb, int M, int N, int K, int relu){
    int blocks = (M >> 7) * (N >> 7);
    gemm_k<<<dim3(blocks), dim3(256), 0, stream>>>(A, Bt, bias, resid, Cf, Cb, M, N, K, relu);
  };

  // weight repack (all layers, once per call)
  repack_qkv_k<<<dim3(32,96,3),  dim3(32,32), 0, stream>>>(wq, wk, wv, qkvT);
  repack_t_k  <<<dim3(32,32,3),  dim3(32,32), 0, stream>>>(w_proj, projT, 1024, 1024, (size_t)1048576, (size_t)1048576);
  repack_t_k  <<<dim3(128,32,3), dim3(32,32), 0, stream>>>(w1, w1T, 1024, 4096, (size_t)4194304, (size_t)4194304);
  repack_t_k  <<<dim3(32,128,3), dim3(32,32), 0, stream>>>(w2, w2T, 4096, 1024, (size_t)4194304, (size_t)4194304);
  repack_t_k  <<<dim3(1000,32,1),dim3(32,32), 0, stream>>>(w_lm, wlmT, 1024, VOC, (size_t)0, (size_t)0);

  embed_k<<<dim3(MR), dim3(256), 0, stream>>>(idx, tok_emb, pos_emb, x);

  for (int l = 0; l < NL; l++){
    ln_k<<<dim3(MR), dim3(256), 0, stream>>>(x, ln1g + l*1024, ln1b + l*1024, hbuf);
    gemm(hbuf, qkvT + (size_t)l*3072*1024, nullptr, nullptr, nullptr, qkvb, MR, 3072, 1024, 0);
    attn_k<<<dim3(512), dim3(256), 0, stream>>>(qkvb, attnb);
    gemm(attnb, projT + (size_t)l*1048576, b_proj + l*1024, nullptr, sa, nullptr, MR, 1024, 1024, 0);
    ln_k<<<dim3(MR), dim3(256), 0, stream>>>(x, ln2g + l*1024, ln2b + l*1024, hbuf);
    gemm(hbuf, w1T + (size_t)l*4194304, b1 + l*4096, nullptr, nullptr, ff1, MR, 4096, 1024, 1);
    // x_new = ff2 + b2 + sa   (reference: x = sa + ff, no residual x)
    gemm(ff1, w2T + (size_t)l*4194304, b2 + l*1024, sa, x, nullptr, MR, 1024, 4096, 0);
  }
  ln_k<<<dim3(MR), dim3(256), 0, stream>>>(x, lnfg, lnfb, hbuf);
  gemm(hbuf, wlmT, b_lm, nullptr, (float*)d_out, nullptr, MR, VOC, 1024, 0);
}

// Round 4
// 1543.606 us; speedup vs baseline: 1.0900x; 1.0900x over previous
//
#include <hip/hip_runtime.h>

// ---- model constants ----
#define D_    1024
#define T_    1024
#define H_    16
#define HD_   64
#define NL    3
#define VOC   32000
#define BAT   2
#define MR    (BAT*T_)   // 2048 rows

typedef unsigned short u16;
typedef unsigned int   u32;
typedef __bf16 bf16x8 __attribute__((ext_vector_type(8)));
typedef float  f32x4  __attribute__((ext_vector_type(4)));

__device__ __forceinline__ u16 f2b(float f){
  u32 u = __float_as_uint(f);
  u += 0x7fffu + ((u >> 16) & 1u);          // RNE; inputs finite
  return (u16)(u >> 16);
}
__device__ __forceinline__ float blo(u32 w){ return __uint_as_float(w << 16); }
__device__ __forceinline__ float bhi(u32 w){ return __uint_as_float(w & 0xffff0000u); }
__device__ __forceinline__ u32 pk2(float a, float b){ return (u32)f2b(a) | ((u32)f2b(b) << 16); }

// async global->LDS, 16B per lane; LDS dest is wave-uniform base + lane*16 (linear)
__device__ __forceinline__ void gload16(const u16* g, u16* l){
  __builtin_amdgcn_global_load_lds(
      (const __attribute__((address_space(1))) void*)g,
      (__attribute__((address_space(3))) void*)l, 16, 0, 0);
}

// ---- embedding: x[bt][d] = tok_emb[idx[bt]][d] + pos_emb[t][d] ----
__global__ __launch_bounds__(256) void embed_k(const int* __restrict__ idx,
    const float* __restrict__ tok, const float* __restrict__ pos, float* __restrict__ x){
  int bt = blockIdx.x, tid = threadIdx.x;
  int t = bt & (T_-1);
  int tk = idx[bt];
  float4 a = ((const float4*)(tok + (size_t)tk * D_))[tid];
  float4 p = ((const float4*)(pos + (size_t)t  * D_))[tid];
  a.x += p.x; a.y += p.y; a.z += p.z; a.w += p.w;
  ((float4*)(x + (size_t)bt * D_))[tid] = a;
}

// ---- layernorm (f32 in, bf16 out), one block per row of 1024 ----
__global__ __launch_bounds__(256) void ln_k(const float* __restrict__ x,
    const float* __restrict__ g, const float* __restrict__ b, u16* __restrict__ out){
  int row = blockIdx.x, tid = threadIdx.x;
  float4 v = ((const float4*)(x + (size_t)row * D_))[tid];
  float s = v.x+v.y+v.z+v.w;
  float q = v.x*v.x+v.y*v.y+v.z*v.z+v.w*v.w;
  #pragma unroll
  for (int off = 32; off >= 1; off >>= 1){
    s += __shfl_xor(s, off);
    q += __shfl_xor(q, off);
  }
  __shared__ float ss[4], sq[4];
  int wave = tid >> 6;
  if ((tid & 63) == 0){ ss[wave] = s; sq[wave] = q; }
  __syncthreads();
  s = ss[0]+ss[1]+ss[2]+ss[3];
  q = sq[0]+sq[1]+sq[2]+sq[3];
  float mean = s * (1.f/D_);
  float var  = q * (1.f/D_) - mean*mean;
  float rs = rsqrtf(var + 1e-5f);
  float4 gg = ((const float4*)g)[tid];
  float4 bb = ((const float4*)b)[tid];
  u32 p0 = pk2((v.x-mean)*rs*gg.x+bb.x, (v.y-mean)*rs*gg.y+bb.y);
  u32 p1 = pk2((v.z-mean)*rs*gg.z+bb.z, (v.w-mean)*rs*gg.w+bb.w);
  ((uint2*)(out + (size_t)row * D_))[tid] = make_uint2(p0, p1);
}

// ---- weight repack: f32 [K,N] -> bf16 [N,K] (B^T), LDS-tiled transpose ----
__global__ __launch_bounds__(1024) void repack_t_k(const float* __restrict__ src,
    u16* __restrict__ dst, int K, int N, size_t sstride, size_t dstride){
  __shared__ float tile[32][33];
  int l = blockIdx.z;
  const float* s = src + (size_t)l * sstride;
  u16* d = dst + (size_t)l * dstride;
  int n0 = blockIdx.x << 5, k0 = blockIdx.y << 5;
  int tx = threadIdx.x, ty = threadIdx.y;
  tile[ty][tx] = s[(size_t)(k0 + ty) * N + n0 + tx];
  __syncthreads();
  d[(size_t)(n0 + ty) * K + k0 + tx] = f2b(tile[tx][ty]);
}

// ---- qkv repack: wq/wk/wv (L,H,D,HD) f32 -> bf16 [L][3072][1024] (n = which*1024+h*64+hd, transposed vs d) ----
__global__ __launch_bounds__(1024) void repack_qkv_k(const float* __restrict__ wq,
    const float* __restrict__ wk, const float* __restrict__ wv, u16* __restrict__ dst){
  __shared__ float tile[32][33];
  int l = blockIdx.z;
  int d0 = blockIdx.x << 5;
  int n0 = blockIdx.y << 5;
  int which = n0 >> 10, within = n0 & 1023;
  int hh = within >> 6, hd0 = within & 63;
  const float* src = (which == 0 ? wq : (which == 1 ? wk : wv))
                     + ((size_t)l * H_ + hh) * (D_ * HD_);
  int tx = threadIdx.x, ty = threadIdx.y;
  tile[ty][tx] = src[(size_t)(d0 + ty) * HD_ + hd0 + tx];
  __syncthreads();
  dst[((size_t)l * 3072 + n0 + ty) * D_ + d0 + tx] = f2b(tile[tx][ty]);
}

// ---- bf16 MFMA GEMM: C[M,N] = A[M,K] @ Bt[N,K]^T (+bias)(+resid)(relu?) ----
// 128x128 tile, BK=32, 4 waves, each wave 64x64 via 4x4 mfma_f32_16x16x32_bf16.
// 2-phase LDS double-buffer: prefetch tile k+1 via global_load_lds (width=16)
// BEFORE computing tile k; single barrier per K-step so the compiler's
// vmcnt(0)-before-s_barrier drain overlaps with ds_read+MFMA (T3-lite recipe).
// Bank-conflict-free via XOR swizzle of 16B segment with (row>>1)&3 applied to
// BOTH the global source address (involution) and the ds_read address; LDS dest
// stays linear (rule #21). Tile order group-major (8 n-tiles x all m-tiles).
// K must be a multiple of 64 (holds: 1024/4096).
__global__ __launch_bounds__(256) void gemm_k(
    const u16* __restrict__ A, const u16* __restrict__ Bt,
    const float* __restrict__ bias, const float* __restrict__ resid,
    float* __restrict__ Cf, u16* __restrict__ Cb,
    int M, int N, int K, int relu)
{
  __shared__ __attribute__((aligned(16))) u16 Als0[128*32];
  __shared__ __attribute__((aligned(16))) u16 Bls0[128*32];
  __shared__ __attribute__((aligned(16))) u16 Als1[128*32];
  __shared__ __attribute__((aligned(16))) u16 Bls1[128*32];
  int tiles_m = M >> 7, tiles_n = N >> 7;
  int tm, tn;
  {
    const int GN = 8;
    int full = tiles_n / GN;
    int fullsz = full * GN * tiles_m;
    int bid = blockIdx.x;
    if (bid < fullsz){
      int g = bid / (GN * tiles_m);
      int r = bid % (GN * tiles_m);
      tm = r / GN; tn = g * GN + (r % GN);
    } else {
      int r = bid - fullsz;
      int remn = tiles_n - full * GN;
      tm = r / remn; tn = full * GN + (r % remn);
    }
  }
  int m0 = tm << 7, n0 = tn << 7;
  int tid = threadIdx.x, lane = tid & 63, wave = tid >> 6;
  int wm = (wave >> 1) << 6, wn = (wave & 1) << 6;
  f32x4 acc[4][4];
  f32x4 zero = {0.f, 0.f, 0.f, 0.f};
  #pragma unroll
  for (int i = 0; i < 4; i++)
    #pragma unroll
    for (int j = 0; j < 4; j++) acc[i][j] = zero;

  // staging geometry: wave w covers LDS rows [w*16, w*16+16) and +64; lane l -> row w*16+(l>>2), seg l&3
  int lrow = lane >> 2, lseg = lane & 3;
  int arow = wave*16 + lrow;                 // LDS row index (first half)
  int ssw  = (arow >> 1) & 3;                // segment swizzle ((row+64) gives same)
  int scol = ((lseg ^ ssw) << 3);            // swizzled source column (elements)
  const u16* Ag0 = A  + (size_t)(m0 + arow) * K + scol;
  const u16* Ag1 = Ag0 + (size_t)64 * K;
  const u16* Bg0 = Bt + (size_t)(n0 + arow) * K + scol;
  const u16* Bg1 = Bg0 + (size_t)64 * K;
  int lofs = wave*512;                       // 16 rows * 32 elems

  int fr = lane & 15;
  int fqs = (((lane >> 4) ^ ((fr >> 1) & 3)) << 3);   // swizzled read offset within row

  #define STAGE(AL, BL, KO) do { \
    gload16(Ag0 + (KO), (AL) + lofs); \
    gload16(Ag1 + (KO), (AL) + 64*32 + lofs); \
    gload16(Bg0 + (KO), (BL) + lofs); \
    gload16(Bg1 + (KO), (BL) + 64*32 + lofs); \
  } while(0)

  #define COMPUTE(AL, BL) do { \
    bf16x8 af[4], bfr[4]; \
    _Pragma("unroll") \
    for (int i = 0; i < 4; i++) af[i]  = *(const bf16x8*)((AL) + (wm + i*16 + fr)*32 + fqs); \
    _Pragma("unroll") \
    for (int i = 0; i < 4; i++) bfr[i] = *(const bf16x8*)((BL) + (wn + i*16 + fr)*32 + fqs); \
    _Pragma("unroll") \
    for (int mi = 0; mi < 4; mi++) \
      _Pragma("unroll") \
      for (int ni = 0; ni < 4; ni++) \
        acc[mi][ni] = __builtin_amdgcn_mfma_f32_16x16x32_bf16(af[mi], bfr[ni], acc[mi][ni], 0, 0, 0); \
  } while(0)

  STAGE(Als0, Bls0, 0);
  __syncthreads();                            // drain prologue stage
  for (int k0 = 0; k0 < K; k0 += 64){
    // phase A: prefetch k0+32 -> buf1, compute k0 from buf0
    STAGE(Als1, Bls1, k0 + 32);
    COMPUTE(Als0, Bls0);
    __syncthreads();                          // buf1 staged + buf0 reads done
    // phase B: prefetch k0+64 -> buf0, compute k0+32 from buf1
    if (k0 + 64 < K) STAGE(Als0, Bls0, k0 + 64);
    COMPUTE(Als1, Bls1);
    __syncthreads();                          // buf0 staged + buf1 reads done
  }
  #undef STAGE
  #undef COMPUTE

  // epilogue: C/D layout col=lane&15, row=(lane>>4)*4+reg  [guide-verified m89/m91]
  int cn = lane & 15, rq = (lane >> 4) << 2;
  #pragma unroll
  for (int mi = 0; mi < 4; mi++){
    #pragma unroll
    for (int ni = 0; ni < 4; ni++){
      int c = n0 + wn + ni*16 + cn;
      float bv = bias ? bias[c] : 0.f;
      #pragma unroll
      for (int r = 0; r < 4; r++){
        int rr = m0 + wm + mi*16 + rq + r;
        float v = acc[mi][ni][r] + bv;
        if (resid) v += resid[(size_t)rr * N + c];
        if (relu)  v = fmaxf(v, 0.f);
        if (Cf) Cf[(size_t)rr * N + c] = v;
        if (Cb) Cb[(size_t)rr * N + c] = f2b(v);
      }
    }
  }
}

// ---- MFMA causal flash attention ----
// grid: B*H*(T/64) = 512 blocks, 256 thr = 4 waves; each wave owns 16 query rows.
// qkv: [B*T][3072] bf16 (q|k|v, each [*][h*64+d]); out: [B*T][1024] bf16 (h-major)
__global__ __launch_bounds__(256) void attn_k(const u16* __restrict__ qkv, u16* __restrict__ out){
  __shared__ u16 kls[64][72];        // K[s][d]
  __shared__ u16 vtls[64][72];       // V^T[d][s]
  __shared__ u16 pls[4][16][72];     // per-wave P tile [q][s]
  int bid = blockIdx.x;
  int qt = bid & 15, bh = bid >> 4;          // 16 q-tiles of 64 rows
  int h = bh & (H_-1), b = bh >> 4;
  int q0 = qt << 6;
  int tid = threadIdx.x, lane = tid & 63, wave = tid >> 6;
  int fr = lane & 15, fq = (lane >> 4) << 3; // A/B frag: row/col = lane&15, k = (lane>>4)*8
  int cn = fr, rq = (lane >> 4) << 2;        // C frag: col = lane&15, row = (lane>>4)*4 + r

  // Q fragments (16 rows x 64 cols per wave), loaded once
  const u16* qp = qkv + ((size_t)(b*T_ + q0 + wave*16 + fr) * 3072 + h*64);
  bf16x8 qa0 = *(const bf16x8*)(qp + fq);
  bf16x8 qa1 = *(const bf16x8*)(qp + 32 + fq);

  f32x4 acc[4];
  f32x4 zero = {0.f,0.f,0.f,0.f};
  #pragma unroll
  for (int i = 0; i < 4; i++) acc[i] = zero;
  float mrun[4], lrun[4];
  #pragma unroll
  for (int r = 0; r < 4; r++){ mrun[r] = -1e30f; lrun[r] = 0.f; }

  // staging: rows 0..31 (+32 partner), 8 threads per row cover all 64 cols
  int ldrow = tid >> 3, ldseg = tid & 7;
  const u16* kbase = qkv + ((size_t)(b*T_ + ldrow) * 3072 + 1024 + h*64 + ldseg*8);
  const size_t rstep = (size_t)32 * 3072;

  for (int ch = 0; ch <= qt; ch++){
    const u16* kp = kbase + (size_t)(ch << 6) * 3072;
    uint4 kv0 = *(const uint4*)kp;
    uint4 kv1 = *(const uint4*)(kp + rstep);
    uint4 vv0 = *(const uint4*)(kp + 1024);
    uint4 vv1 = *(const uint4*)(kp + rstep + 1024);
    __syncthreads();                          // prev iter done reading kls/vtls
    *(uint4*)(&kls[ldrow][ldseg*8])      = kv0;
    *(uint4*)(&kls[ldrow + 32][ldseg*8]) = kv1;
    union { uint4 u; u16 s[8]; } vu0, vu1; vu0.u = vv0; vu1.u = vv1;
    #pragma unroll
    for (int j = 0; j < 8; j++){
      vtls[ldseg*8 + j][ldrow]      = vu0.s[j];
      vtls[ldseg*8 + j][ldrow + 32] = vu1.s[j];
    }
    __syncthreads();

    // S = Q @ K^T  (16x64 per wave)
    f32x4 sf[4];
    #pragma unroll
    for (int ni = 0; ni < 4; ni++) sf[ni] = zero;
    #pragma unroll
    for (int ni = 0; ni < 4; ni++){
      bf16x8 kb0 = *(const bf16x8*)(&kls[ni*16 + fr][fq]);
      bf16x8 kb1 = *(const bf16x8*)(&kls[ni*16 + fr][32 + fq]);
      sf[ni] = __builtin_amdgcn_mfma_f32_16x16x32_bf16(qa0, kb0, sf[ni], 0, 0, 0);
      sf[ni] = __builtin_amdgcn_mfma_f32_16x16x32_bf16(qa1, kb1, sf[ni], 0, 0, 0);
    }

    int s0 = ch << 6;
    float sv[4][4];
    if (ch == qt){                            // diagonal chunk: causal mask
      #pragma unroll
      for (int ni = 0; ni < 4; ni++)
        #pragma unroll
        for (int r = 0; r < 4; r++){
          int srow = s0 + ni*16 + cn;
          int qrow = q0 + wave*16 + rq + r;
          sv[ni][r] = (srow <= qrow) ? sf[ni][r]*0.125f : -1e30f;
        }
    } else {
      #pragma unroll
      for (int ni = 0; ni < 4; ni++)
        #pragma unroll
        for (int r = 0; r < 4; r++) sv[ni][r] = sf[ni][r]*0.125f;
    }

    // online softmax: row = 16 lanes sharing (lane>>4), reduce via shfl_xor 1..8
    #pragma unroll
    for (int r = 0; r < 4; r++){
      float mx = fmaxf(fmaxf(sv[0][r], sv[1][r]), fmaxf(sv[2][r], sv[3][r]));
      #pragma unroll
      for (int off = 8; off >= 1; off >>= 1) mx = fmaxf(mx, __shfl_xor(mx, off));
      float mn = fmaxf(mrun[r], mx);
      float al = __expf(mrun[r] - mn);
      mrun[r] = mn;
      float ps = 0.f;
      #pragma unroll
      for (int ni = 0; ni < 4; ni++){
        float p = __expf(sv[ni][r] - mn);
        sv[ni][r] = p; ps += p;
      }
      #pragma unroll
      for (int off = 8; off >= 1; off >>= 1) ps += __shfl_xor(ps, off);
      lrun[r] = lrun[r]*al + ps;
      #pragma unroll
      for (int ni = 0; ni < 4; ni++) acc[ni][r] *= al;
    }

    // P (C layout) -> LDS -> A-fragments
    #pragma unroll
    for (int ni = 0; ni < 4; ni++)
      #pragma unroll
      for (int r = 0; r < 4; r++)
        pls[wave][rq + r][ni*16 + cn] = f2b(sv[ni][r]);
    __syncthreads();

    // O += P @ V   (A = P[q][s], Bt = V^T[d][s])
    #pragma unroll
    for (int kk = 0; kk < 2; kk++){
      bf16x8 pa = *(const bf16x8*)(&pls[wave][fr][kk*32 + fq]);
      #pragma unroll
      for (int di = 0; di < 4; di++){
        bf16x8 vb = *(const bf16x8*)(&vtls[di*16 + fr][kk*32 + fq]);
        acc[di] = __builtin_amdgcn_mfma_f32_16x16x32_bf16(pa, vb, acc[di], 0, 0, 0);
      }
    }
  }

  u16* ob = out + ((size_t)(b*T_ + q0 + wave*16) * D_ + h*64);
  #pragma unroll
  for (int r = 0; r < 4; r++){
    float inv = 1.f / lrun[r];
    #pragma unroll
    for (int di = 0; di < 4; di++)
      ob[(size_t)(rq + r) * D_ + di*16 + cn] = f2b(acc[di][r] * inv);
  }
}

extern "C" void kernel_launch(void* const* d_in, const int* in_sizes, int n_in,
                              void* d_out, int out_size, void* d_ws, size_t ws_size,
                              hipStream_t stream){
  (void)in_sizes; (void)n_in; (void)out_size; (void)ws_size;
  const int*   idx     = (const int*)  d_in[0];
  const float* tok_emb = (const float*)d_in[1];
  const float* pos_emb = (const float*)d_in[2];
  const float* wq      = (const float*)d_in[3];
  const float* wk      = (const float*)d_in[4];
  const float* wv      = (const float*)d_in[5];
  const float* w_proj  = (const float*)d_in[6];
  const float* b_proj  = (const float*)d_in[7];
  const float* w1      = (const float*)d_in[8];
  const float* b1      = (const float*)d_in[9];
  const float* w2      = (const float*)d_in[10];
  const float* b2      = (const float*)d_in[11];
  const float* ln1g    = (const float*)d_in[12];
  const float* ln1b    = (const float*)d_in[13];
  const float* ln2g    = (const float*)d_in[14];
  const float* ln2b    = (const float*)d_in[15];
  const float* lnfg    = (const float*)d_in[16];
  const float* lnfb    = (const float*)d_in[17];
  const float* w_lm    = (const float*)d_in[18];
  const float* b_lm    = (const float*)d_in[19];

  char* ws = (char*)d_ws;
  size_t off = 0;
  auto alloc = [&](size_t bytes)->char*{
    char* p = ws + off; off += (bytes + 255) & ~(size_t)255; return p;
  };
  u16*   qkvT  = (u16*)  alloc((size_t)NL*3072*1024*2);
  u16*   projT = (u16*)  alloc((size_t)NL*1024*1024*2);
  u16*   w1T   = (u16*)  alloc((size_t)NL*4096*1024*2);
  u16*   w2T   = (u16*)  alloc((size_t)NL*1024*4096*2);
  u16*   wlmT  = (u16*)  alloc((size_t)VOC*1024*2);
  float* x     = (float*)alloc((size_t)MR*1024*4);
  u16*   hbuf  = (u16*)  alloc((size_t)MR*1024*2);
  u16*   qkvb  = (u16*)  alloc((size_t)MR*3072*2);
  u16*   attnb = (u16*)  alloc((size_t)MR*1024*2);
  float* sa    = (float*)alloc((size_t)MR*1024*4);
  u16*   ff1   = (u16*)  alloc((size_t)MR*4096*2);

  auto gemm = [&](const u16* A, const u16* Bt, const float* bias, const float* resid,
                  float* Cf, u16* Cb, int M, int N, int K, int relu){
    int blocks = (M >> 7) * (N >> 7);
    gemm_k<<<dim3(blocks), dim3(256), 0, stream>>>(A, Bt, bias, resid, Cf, Cb, M, N, K, relu);
  };

  // weight repack (all layers, once per call)
  repack_qkv_k<<<dim3(32,96,3),  dim3(32,32), 0, stream>>>(wq, wk, wv, qkvT);
  repack_t_k  <<<dim3(32,32,3),  dim3(32,32), 0, stream>>>(w_proj, projT, 1024, 1024, (size_t)1048576, (size_t)1048576);
  repack_t_k  <<<dim3(128,32,3), dim3(32,32), 0, stream>>>(w1, w1T, 1024, 4096, (size_t)4194304, (size_t)4194304);
  repack_t_k  <<<dim3(32,128,3), dim3(32,32), 0, stream>>>(w2, w2T, 4096, 1024, (size_t)4194304, (size_t)4194304);
  repack_t_k  <<<dim3(1000,32,1),dim3(32,32), 0, stream>>>(w_lm, wlmT, 1024, VOC, (size_t)0, (size_t)0);

  embed_k<<<dim3(MR), dim3(256), 0, stream>>>(idx, tok_emb, pos_emb, x);

  for (int l = 0; l < NL; l++){
    ln_k<<<dim3(MR), dim3(256), 0, stream>>>(x, ln1g + l*1024, ln1b + l*1024, hbuf);
    gemm(hbuf, qkvT + (size_t)l*3072*1024, nullptr, nullptr, nullptr, qkvb, MR, 3072, 1024, 0);
    attn_k<<<dim3(512), dim3(256), 0, stream>>>(qkvb, attnb);
    gemm(attnb, projT + (size_t)l*1048576, b_proj + l*1024, nullptr, sa, nullptr, MR, 1024, 1024, 0);
    ln_k<<<dim3(MR), dim3(256), 0, stream>>>(x, ln2g + l*1024, ln2b + l*1024, hbuf);
    gemm(hbuf, w1T + (size_t)l*4194304, b1 + l*4096, nullptr, nullptr, ff1, MR, 4096, 1024, 1);
    // x_new = ff2 + b2 + sa   (reference: x = sa + ff, no residual x)
    gemm(ff1, w2T + (size_t)l*4194304, b2 + l*1024, sa, x, nullptr, MR, 1024, 4096, 0);
  }
  ln_k<<<dim3(MR), dim3(256), 0, stream>>>(x, lnfg, lnfb, hbuf);
  gemm(hbuf, wlmT, b_lm, nullptr, (float*)d_out, nullptr, MR, VOC, 1024, 0);
}